// Round 2
// baseline (2760.146 us; speedup 1.0000x reference)
//
#include <hip/hip_runtime.h>

// GAT aggregate: N=100000 nodes, K=16 neighbors, D=128, DOUT=128, all fp32.
// out[n] = relu( softmax([<self,neigh_k>]_k) . [neigh;self] @ W )
//
// One wave per node-PAIR (2 nodes per iteration for ILP); lane l owns feature
// dims {2l, 2l+1}. W staged once per block in LDS, interleaved so one
// ds_read_b128 serves two d-rows x two output columns, shared by both nodes.
// 512-thread blocks + 64KiB LDS -> 2 blocks/CU = 16 waves/CU (VGPR cap too).

constexpr int K    = 16;
constexpr int D    = 128;
constexpr int DOUT = 128;

__launch_bounds__(512, 4)
__global__ void gat_kernel(const float* __restrict__ self_vecs,
                           const float* __restrict__ neigh_vecs,
                           const float* __restrict__ W,
                           float* __restrict__ out,
                           int n_nodes, int total_waves) {
    // Interleaved W: float4 slot s = p*64 + l holds
    //   { W[2p][2l], W[2p][2l+1], W[2p+1][2l], W[2p+1][2l+1] }
    __shared__ float Ws[D * DOUT];  // 64 KiB

    const int tid = threadIdx.x;

    for (int s = tid; s < (D * DOUT) / 4; s += blockDim.x) {
        const int p = s >> 6;
        const int l = s & 63;
        const float* r0 = W + (size_t)(2 * p) * DOUT + 2 * l;
        const float2 a = *(const float2*)r0;
        const float2 b = *(const float2*)(r0 + DOUT);
        ((float4*)Ws)[s] = make_float4(a.x, a.y, b.x, b.y);
    }
    __syncthreads();

    const int lane = tid & 63;
    const int wave = blockIdx.x * (blockDim.x >> 6) + (tid >> 6);
    const int npairs = (n_nodes + 1) >> 1;

    for (int pr = wave; pr < npairs; pr += total_waves) {
        const int na = 2 * pr;
        const int hasb = (na + 1 < n_nodes);
        const int nidx[2] = { na, hasb ? na + 1 : na };

        // ---- load self + 16 neighbors for both nodes (float2/lane, coalesced) ----
        float2 v[2][K + 1];
        #pragma unroll
        for (int u = 0; u < 2; ++u) {
            const float* nbp = neigh_vecs + (size_t)nidx[u] * K * D + 2 * lane;
            #pragma unroll
            for (int k = 0; k < K; ++k)
                v[u][k] = *(const float2*)(nbp + (size_t)k * D);
            v[u][K] = *(const float2*)(self_vecs + (size_t)nidx[u] * D + 2 * lane);
        }

        // ---- 17 dots per node, butterfly allreduce (two independent chains) ----
        float sc[2][K + 1];
        #pragma unroll
        for (int u = 0; u < 2; ++u) {
            const float2 sv = v[u][K];
            #pragma unroll
            for (int k = 0; k <= K; ++k) {
                float p = sv.x * v[u][k].x + sv.y * v[u][k].y;
                #pragma unroll
                for (int off = 32; off; off >>= 1)
                    p += __shfl_xor(p, off);
                sc[u][k] = p;
            }
        }

        // ---- stable softmax + context (1/sum folded into one final scale) ----
        float cx[2], cy[2];
        #pragma unroll
        for (int u = 0; u < 2; ++u) {
            float m = sc[u][0];
            #pragma unroll
            for (int k = 1; k <= K; ++k) m = fmaxf(m, sc[u][k]);
            float sum = 0.f, ax = 0.f, ay = 0.f;
            #pragma unroll
            for (int k = 0; k <= K; ++k) {
                const float e = __expf(sc[u][k] - m);
                sum += e;
                ax += e * v[u][k].x;
                ay += e * v[u][k].y;
            }
            const float inv = 1.0f / sum;
            cx[u] = ax * inv;
            cy[u] = ay * inv;
        }

        // ---- out = relu(ctx @ W); one b128 W-read serves both nodes ----
        float a0 = 0.f, a1 = 0.f, b0 = 0.f, b1 = 0.f;
        #pragma unroll
        for (int p = 0; p < D / 2; ++p) {
            const float4 w = ((const float4*)Ws)[p * 64 + lane];
            const float c0a = __shfl(cx[0], p);
            const float c1a = __shfl(cy[0], p);
            const float c0b = __shfl(cx[1], p);
            const float c1b = __shfl(cy[1], p);
            a0 += c0a * w.x + c1a * w.z;
            a1 += c0a * w.y + c1a * w.w;
            b0 += c0b * w.x + c1b * w.z;
            b1 += c0b * w.y + c1b * w.w;
        }
        *(float2*)(out + (size_t)na * DOUT + 2 * lane) =
            make_float2(fmaxf(a0, 0.f), fmaxf(a1, 0.f));
        if (hasb)
            *(float2*)(out + (size_t)(na + 1) * DOUT + 2 * lane) =
                make_float2(fmaxf(b0, 0.f), fmaxf(b1, 0.f));
    }
}

extern "C" void kernel_launch(void* const* d_in, const int* in_sizes, int n_in,
                              void* d_out, int out_size, void* d_ws, size_t ws_size,
                              hipStream_t stream) {
    const float* self_vecs = (const float*)d_in[0];
    const float* neigh     = (const float*)d_in[1];
    const float* W         = (const float*)d_in[2];
    float* out = (float*)d_out;

    const int n_nodes = in_sizes[0] / D;  // 100000

    const int tpb = 512;                  // 8 waves
    const int blocks = 512;               // 2 blocks/CU x 256 CU (64KiB LDS each)
    const int total_waves = blocks * (tpb / 64);

    gat_kernel<<<dim3(blocks), dim3(tpb), 0, stream>>>(
        self_vecs, neigh, W, out, n_nodes, total_waves);
}

// Round 4
// 2278.016 us; speedup vs baseline: 1.2116x; 1.2116x over previous
//
#include <hip/hip_runtime.h>

// GAT aggregate: N=100000, K=16, D=128, DOUT=128, fp32.
// out[n] = relu( softmax([<self,neigh_k>]_k ++ <self,self>) . [neigh;self] @ W )
//
// One wave per node-PAIR; lane l owns dims {2l,2l+1}. Proven __shfl_xor
// butterfly for the 64-lane dot reduce (R1-verified). Online softmax keeps the
// register footprint ~110 VGPR so 512-thr blocks fit 2 blocks/CU (16 waves/CU,
// double R1's occupancy). W staged once per block in LDS, interleaved so one
// ds_read_b128 serves two d-rows x two output columns, shared by both nodes.
//
// NOTE: __launch_bounds__ arg2 behaves CUDA-style (min BLOCKS/CU) on this
// toolchain: (512,4) observed VGPR cap 64 (R2), so (512,2) -> cap 128.

constexpr int K    = 16;
constexpr int D    = 128;
constexpr int DOUT = 128;

__device__ __forceinline__ float wave_allsum(float x) {
    #pragma unroll
    for (int off = 32; off; off >>= 1)
        x += __shfl_xor(x, off);
    return x;
}

__launch_bounds__(512, 2)
__global__ void gat_kernel(const float* __restrict__ self_vecs,
                           const float* __restrict__ neigh_vecs,
                           const float* __restrict__ W,
                           float* __restrict__ out,
                           int n_nodes, int total_waves) {
    // Interleaved W: float4 slot s = p*64 + l holds
    //   { W[2p][2l], W[2p][2l+1], W[2p+1][2l], W[2p+1][2l+1] }
    __shared__ float Ws[D * DOUT];  // 64 KiB -> 2 blocks/CU -> 16 waves/CU

    const int tid = threadIdx.x;
    for (int s = tid; s < (D * DOUT) / 4; s += blockDim.x) {
        const int p = s >> 6;
        const int l = s & 63;
        const float* r0 = W + (size_t)(2 * p) * DOUT + 2 * l;
        const float2 a = *(const float2*)r0;
        const float2 b = *(const float2*)(r0 + DOUT);
        ((float4*)Ws)[s] = make_float4(a.x, a.y, b.x, b.y);
    }
    __syncthreads();

    const int lane = tid & 63;
    const int wave = blockIdx.x * (blockDim.x >> 6) + (tid >> 6);
    const int npairs = (n_nodes + 1) >> 1;

    for (int pr = wave; pr < npairs; pr += total_waves) {
        const int na = 2 * pr;
        const int nb = (na + 1 < n_nodes) ? na + 1 : na;

        // ---- batched coalesced loads (17 float2/lane per node, all in flight) ----
        const float* pa_ = neigh_vecs + (size_t)na * K * D + 2 * lane;
        const float* pb_ = neigh_vecs + (size_t)nb * K * D + 2 * lane;
        float2 va[K], vb[K];
        #pragma unroll
        for (int k = 0; k < K; ++k) va[k] = *(const float2*)(pa_ + (size_t)k * D);
        #pragma unroll
        for (int k = 0; k < K; ++k) vb[k] = *(const float2*)(pb_ + (size_t)k * D);
        const float2 sa = *(const float2*)(self_vecs + (size_t)na * D + 2 * lane);
        const float2 sb = *(const float2*)(self_vecs + (size_t)nb * D + 2 * lane);

        // ---- online softmax + context, initialized from the self term (e^0) ----
        float ma = wave_allsum(sa.x * sa.x + sa.y * sa.y);
        float mb = wave_allsum(sb.x * sb.x + sb.y * sb.y);
        float suma = 1.f, sumb = 1.f;
        float cxa = sa.x, cya = sa.y;
        float cxb = sb.x, cyb = sb.y;

        #pragma unroll
        for (int k = 0; k < K; ++k) {
            const float da = wave_allsum(sa.x * va[k].x + sa.y * va[k].y);
            const float db = wave_allsum(sb.x * vb[k].x + sb.y * vb[k].y);
            {
                const float mn = fmaxf(ma, da);
                const float sc = __expf(ma - mn);
                const float e  = __expf(da - mn);
                suma = suma * sc + e;
                cxa  = cxa * sc + e * va[k].x;
                cya  = cya * sc + e * va[k].y;
                ma = mn;
            }
            {
                const float mn = fmaxf(mb, db);
                const float sc = __expf(mb - mn);
                const float e  = __expf(db - mn);
                sumb = sumb * sc + e;
                cxb  = cxb * sc + e * vb[k].x;
                cyb  = cyb * sc + e * vb[k].y;
                mb = mn;
            }
        }
        const float inva = 1.f / suma, invb = 1.f / sumb;
        cxa *= inva; cya *= inva;
        cxb *= invb; cyb *= invb;

        // ---- out = relu(ctx @ W); one b128 W-read serves both nodes ----
        float a0 = 0.f, a1 = 0.f, b0 = 0.f, b1 = 0.f;
        #pragma unroll
        for (int p = 0; p < D / 2; ++p) {
            const float4 w = ((const float4*)Ws)[p * 64 + lane];
            const float c0a = __shfl(cxa, p);
            const float c1a = __shfl(cya, p);
            const float c0b = __shfl(cxb, p);
            const float c1b = __shfl(cyb, p);
            a0 += c0a * w.x + c1a * w.z;
            a1 += c0a * w.y + c1a * w.w;
            b0 += c0b * w.x + c1b * w.z;
            b1 += c0b * w.y + c1b * w.w;
        }
        *(float2*)(out + (size_t)na * DOUT + 2 * lane) =
            make_float2(fmaxf(a0, 0.f), fmaxf(a1, 0.f));
        if (nb != na)
            *(float2*)(out + (size_t)nb * DOUT + 2 * lane) =
                make_float2(fmaxf(b0, 0.f), fmaxf(b1, 0.f));
    }
}

extern "C" void kernel_launch(void* const* d_in, const int* in_sizes, int n_in,
                              void* d_out, int out_size, void* d_ws, size_t ws_size,
                              hipStream_t stream) {
    const float* self_vecs = (const float*)d_in[0];
    const float* neigh     = (const float*)d_in[1];
    const float* W         = (const float*)d_in[2];
    float* out = (float*)d_out;

    const int n_nodes = in_sizes[0] / D;  // 100000

    const int tpb = 512;                  // 8 waves/block
    const int blocks = 512;               // 2 blocks/CU x 256 CU (64KiB LDS each)
    const int total_waves = blocks * (tpb / 64);

    gat_kernel<<<dim3(blocks), dim3(tpb), 0, stream>>>(
        self_vecs, neigh, W, out, n_nodes, total_waves);
}

// Round 5
// 318.512 us; speedup vs baseline: 8.6658x; 7.1521x over previous
//
#include <hip/hip_runtime.h>

// GAT aggregate, two-phase: N=100000, K=16, D=128, DOUT=128, fp32.
//   Phase 1 (ctx_kernel):  ctx[n] = softmax(<self_n, [neigh_n;self_n]>) . [neigh_n;self_n]
//                          -> written into d_out (same [N,128] shape as the output)
//   Phase 2 (mlp_kernel):  d_out[n] = relu(ctx[n] @ W), in place.
//
// Rationale (R1-R4 evidence): fused version is boxed in -- 64KiB W tile caps
// LDS at 2 blocks/CU, raising occupancy caps VGPR at 128, and the per-node ILP
// needed to hide 17-load+butterfly chains spills at 128 (R2: VGPR=64 + 7.8GB
// scratch traffic; R4: VGPR=128 + 5.7GB). Splitting lets phase 1 stream with
// zero LDS and small registers, and phase 2 amortize one W LDS-read over 8
// nodes with global wave-uniform ctx broadcasts (no DS, no shfl).
//
// NOTE: __launch_bounds__ arg2 observed CUDA-style (min BLOCKS/CU) on this
// toolchain (R2: (512,4) -> 64-VGPR cap). (256,4)/(256,2) give cap 128/256
// under either interpretation.

constexpr int K    = 16;
constexpr int D    = 128;
constexpr int DOUT = 128;
constexpr int NPW  = 8;   // nodes per wave-iteration in phase 2

__device__ __forceinline__ float wave_allsum(float x) {
    #pragma unroll
    for (int off = 32; off; off >>= 1)
        x += __shfl_xor(x, off);
    return x;
}

// ---------------- Phase 1: attention context (no LDS, no W) ----------------
__launch_bounds__(256, 4)
__global__ void ctx_kernel(const float* __restrict__ self_vecs,
                           const float* __restrict__ neigh_vecs,
                           float* __restrict__ io,
                           int n_nodes) {
    const int lane = threadIdx.x & 63;
    const int n = (int)((blockIdx.x * blockDim.x + threadIdx.x) >> 6);
    if (n >= n_nodes) return;

    // 17 coalesced float2 loads per lane (dims 2l, 2l+1), all in flight
    const float* nbp = neigh_vecs + (size_t)n * (K * D) + 2 * lane;
    float2 v[K];
    #pragma unroll
    for (int k = 0; k < K; ++k) v[k] = *(const float2*)(nbp + (size_t)k * D);
    const float2 s = *(const float2*)(self_vecs + (size_t)n * D + 2 * lane);

    // online softmax + context, initialized from the self term (R4-verified)
    float m = wave_allsum(s.x * s.x + s.y * s.y);
    float sum = 1.f, cx = s.x, cy = s.y;
    #pragma unroll
    for (int k = 0; k < K; ++k) {
        const float d  = wave_allsum(s.x * v[k].x + s.y * v[k].y);
        const float mn = fmaxf(m, d);
        const float sc = __expf(m - mn);
        const float e  = __expf(d - mn);
        sum = sum * sc + e;
        cx  = cx * sc + e * v[k].x;
        cy  = cy * sc + e * v[k].y;
        m = mn;
    }
    const float inv = 1.f / sum;
    *(float2*)(io + (size_t)n * D + 2 * lane) = make_float2(cx * inv, cy * inv);
}

// ---------------- Phase 2: in-place row MLP with relu ----------------
__launch_bounds__(256, 2)
__global__ void mlp_kernel(const float* __restrict__ W,
                           float* __restrict__ io,
                           int n_nodes, int total_waves) {
    // Interleaved W: float4 slot s = p*64 + l holds
    //   { W[2p][2l], W[2p][2l+1], W[2p+1][2l], W[2p+1][2l+1] }  (R1-verified)
    __shared__ float Ws[D * DOUT];  // 64 KiB -> 2 blocks/CU

    const int tid = threadIdx.x;
    for (int sI = tid; sI < (D * DOUT) / 4; sI += blockDim.x) {
        const int p = sI >> 6;
        const int l = sI & 63;
        const float* r0 = W + (size_t)(2 * p) * DOUT + 2 * l;
        const float2 a = *(const float2*)r0;
        const float2 b = *(const float2*)(r0 + DOUT);
        ((float4*)Ws)[sI] = make_float4(a.x, a.y, b.x, b.y);
    }
    __syncthreads();

    const int lane = tid & 63;
    const int wave = blockIdx.x * (blockDim.x >> 6) + (tid >> 6);

    for (int base = wave * NPW; base < n_nodes; base += total_waves * NPW) {
        float a0[NPW], a1[NPW];
        #pragma unroll
        for (int j = 0; j < NPW; ++j) { a0[j] = 0.f; a1[j] = 0.f; }

        #pragma unroll 8
        for (int p = 0; p < D / 2; ++p) {
            // one conflict-free b128 W read serves all NPW nodes
            const float4 w = ((const float4*)Ws)[p * 64 + lane];
            #pragma unroll
            for (int j = 0; j < NPW; ++j) {
                const int n = (base + j < n_nodes) ? base + j : n_nodes - 1;
                // wave-uniform address -> scalar/L1 broadcast, no DS traffic
                const float2 c = *(const float2*)(io + (size_t)n * D + 2 * p);
                a0[j] += c.x * w.x + c.y * w.z;
                a1[j] += c.x * w.y + c.y * w.w;
            }
        }
        // each row is read+written by exactly this wave -> in-place safe
        #pragma unroll
        for (int j = 0; j < NPW; ++j) {
            if (base + j < n_nodes)
                *(float2*)(io + (size_t)(base + j) * DOUT + 2 * lane) =
                    make_float2(fmaxf(a0[j], 0.f), fmaxf(a1[j], 0.f));
        }
    }
}

extern "C" void kernel_launch(void* const* d_in, const int* in_sizes, int n_in,
                              void* d_out, int out_size, void* d_ws, size_t ws_size,
                              hipStream_t stream) {
    const float* self_vecs = (const float*)d_in[0];
    const float* neigh     = (const float*)d_in[1];
    const float* W         = (const float*)d_in[2];
    float* io = (float*)d_out;

    const int n_nodes = in_sizes[0] / D;  // 100000

    // Phase 1: one wave per node
    {
        const int tpb = 256;  // 4 waves
        const int blocks = (n_nodes * 64 + tpb - 1) / tpb;  // 25000
        ctx_kernel<<<dim3(blocks), dim3(tpb), 0, stream>>>(
            self_vecs, neigh, io, n_nodes);
    }
    // Phase 2: grid-stride, 8 nodes per wave-iteration
    {
        const int tpb = 256;     // 4 waves
        const int blocks = 512;  // 2 blocks/CU x 256 CU
        const int total_waves = blocks * (tpb / 64);
        mlp_kernel<<<dim3(blocks), dim3(tpb), 0, stream>>>(
            W, io, n_nodes, total_waves);
    }
}